// Round 1
// baseline (87.472 us; speedup 1.0000x reference)
//
#include <hip/hip_runtime.h>
#include <math.h>

// Problem dims (fixed by reference)
#define BDIM 2048
#define ODIM 256
#define IDIM 256
#define NZ   16                     // j-splits
#define JBLK (IDIM / NZ)            // 16 j per block
#define NJQ  (JBLK / 4)             // 4 j-quads
#define ZBASE ((float)(IDIM / NZ))  // 16.0f exactly; per-z share of the +IDIM base

typedef float v2f __attribute__((ext_vector_type(2)));

// out[b,o] = IDIM + C * sum_j 1/(D - 2at*cos(phi0 + x[b,j] + p[o,j]))
//   C = (t^2-1)(1-a^2),  D = 1+(at)^2
// cos(x'+p) = cos x' cos p - sin x' sin p =>
//   den = D + mc*pc + ms*ps,  mc=-2at*cos(phi0+x), ms=2at*sin(phi0+x)
//
// R10: 128x128 block tile, 8b x 8o per-thread microtile (was 64x64 / 4x4).
// LDS traffic halves: 8/tb+8/to = 2 B/cell (was 4). Per-CU ds_read_b128
// count 2048 -> 1024 over kernel life => LDS floor ~4.3us < VALU floor
// ~6.8us (157 TF f32 roofline). NZ=8->16 keeps 512 blocks = 2/CU
// (8 waves/CU); launch_bounds(256,2) caps VGPR at 256 (working set ~220,
// no spill). A-tile rows padded to 9 float4 => rows ty+16k land on bank
// quads 4*ty mod 32 (conflict-free); P-read keeps free 2-way pattern.

__global__ __launch_bounds__(256, 2)
void photonic_fused(const float* __restrict__ X,   // [BDIM][IDIM]
                    const float* __restrict__ P,   // [ODIM][IDIM]
                    float* __restrict__ Out,       // [BDIM][ODIM] (+= semantics)
                    float phi0, float m2at, float p2at,
                    float Dc, float Cnum) {
    __shared__ float4 As4[128][2 * NJQ + 1];   // [128][9]  = 18432 B (col 8 = pad)
    __shared__ float4 SP4[JBLK][4][16];        // [16][4][16] = 16384 B

    const int tid = threadIdx.x;
    const int tx  = tid & 15;            // o sub-index 0..15
    const int ty  = tid >> 4;            // b sub-index 0..15
    const int o0  = blockIdx.x * 128;
    const int b0  = blockIdx.y * 128;
    const int j0  = blockIdx.z * JBLK;

    // ---- fused prologue: sincos margins straight into f32 LDS ----
    {
        const int r   = tid >> 1;        // 0..127 : row (b for X, o for P)
        const int h   = tid & 1;         // jq pair select
        const int pp  = r >> 5;          // 0..3
        const int hi  = (r >> 4) & 1;    // 0/1
        const int tx_ = r & 15;
        #pragma unroll
        for (int q8 = 0; q8 < 2; ++q8) {
            const int jq = 2 * h + q8;   // h=0:{0,1}  h=1:{2,3}
            float s0, c0, s1, c1, s2, c2, s3, c3;

            float4 x = *(const float4*)(X + (size_t)(b0 + r) * IDIM + j0 + 4 * jq);
            __sincosf(phi0 + x.x, &s0, &c0);
            __sincosf(phi0 + x.y, &s1, &c1);
            __sincosf(phi0 + x.z, &s2, &c2);
            __sincosf(phi0 + x.w, &s3, &c3);
            As4[r][2 * jq]     = make_float4(m2at * c0, m2at * c1, m2at * c2, m2at * c3);
            As4[r][2 * jq + 1] = make_float4(p2at * s0, p2at * s1, p2at * s2, p2at * s3);

            float4 pv = *(const float4*)(P + (size_t)(o0 + r) * IDIM + j0 + 4 * jq);
            __sincosf(pv.x, &s0, &c0);
            __sincosf(pv.y, &s1, &c1);
            __sincosf(pv.z, &s2, &c2);
            __sincosf(pv.w, &s3, &c3);
            float cs[4] = {c0, c1, c2, c3};
            float ss[4] = {s0, s1, s2, s3};
            #pragma unroll
            for (int jj = 0; jj < 4; ++jj) {
                float* cell = (float*)&SP4[4 * jq + jj][pp][tx_];
                cell[hi]     = cs[jj];
                cell[2 + hi] = ss[jj];
            }
        }
    }
    __syncthreads();

    v2f acc[8][4];
    #pragma unroll
    for (int k = 0; k < 8; ++k)
        #pragma unroll
        for (int pp = 0; pp < 4; ++pp) acc[k][pp] = (v2f){0.f, 0.f};

    const v2f D2 = {Dc, Dc};

    #pragma unroll 2
    for (int jq = 0; jq < NJQ; ++jq) {
        // P operands for this j-quad: 16 x b128, shared across all 8 k-rows
        float4 qv[4][4];                       // [pp][j]
        #pragma unroll
        for (int j = 0; j < 4; ++j)
            #pragma unroll
            for (int pp = 0; pp < 4; ++pp)
                qv[pp][j] = SP4[4 * jq + j][pp][tx];

        #pragma unroll
        for (int k = 0; k < 8; ++k) {
            float4 mc4 = As4[ty + 16 * k][2 * jq];
            float4 ms4 = As4[ty + 16 * k][2 * jq + 1];
            float mcf[4] = {mc4.x, mc4.y, mc4.z, mc4.w};
            float msf[4] = {ms4.x, ms4.y, ms4.z, ms4.w};
            #pragma unroll
            for (int pp = 0; pp < 4; ++pp) {
                v2f d[4];
                #pragma unroll
                for (int j = 0; j < 4; ++j) {
                    v2f pc = {qv[pp][j].x, qv[pp][j].y};
                    v2f ps = {qv[pp][j].z, qv[pp][j].w};
                    v2f t = __builtin_elementwise_fma((v2f){msf[j], msf[j]}, ps, D2);
                    d[j]  = __builtin_elementwise_fma((v2f){mcf[j], mcf[j]}, pc, t);
                }
                // quad-rcp over the 4 j's, vectorized over the o-pair
                v2f p01 = d[0] * d[1], p23 = d[2] * d[3];
                v2f s01 = d[0] + d[1], s23 = d[2] + d[3];
                v2f n  = __builtin_elementwise_fma(s01, p23, s23 * p01);
                v2f qq = p01 * p23;
                v2f rr = {__builtin_amdgcn_rcpf(qq.x), __builtin_amdgcn_rcpf(qq.y)};
                acc[k][pp] = __builtin_elementwise_fma(n, rr, acc[k][pp]);
            }
        }
    }

    // ---- atomic epilogue: base folded in as +ZBASE per z-plane ----
    #pragma unroll
    for (int k = 0; k < 8; ++k)
        #pragma unroll
        for (int pp = 0; pp < 4; ++pp) {
            int b = b0 + ty + 16 * k;
            int o = o0 + pp * 32 + tx;
            unsafeAtomicAdd(&Out[(size_t)b * ODIM + o],      fmaf(Cnum, acc[k][pp].x, ZBASE));
            unsafeAtomicAdd(&Out[(size_t)b * ODIM + o + 16], fmaf(Cnum, acc[k][pp].y, ZBASE));
        }
}

extern "C" void kernel_launch(void* const* d_in, const int* in_sizes, int n_in,
                              void* d_out, int out_size, void* d_ws, size_t ws_size,
                              hipStream_t stream) {
    const float* X = (const float*)d_in[0];   // input_matrix [2048,256] f32
    const float* P = (const float*)d_in[1];   // phase_offset [256,256] f32
    float* Out = (float*)d_out;               // [2048,256] f32

    const double RADIUS = 5e-6, KAPPA = 0.1, N_EFF = 3.48, LAMBDA = 1.55e-6, LOSS_A = 0.99;
    const double TWO_PI = 6.283185307179586476925286766559;
    const double t  = sqrt(1.0 - KAPPA);
    const double a  = LOSS_A;
    const double at = a * t;
    const double phi0 = fmod(TWO_PI * N_EFF * (TWO_PI * RADIUS) / LAMBDA, TWO_PI);
    const double D    = 1.0 + at * at;
    const double Cnum = (t * t - 1.0) * (1.0 - a * a);   // num - den (constant)

    // 2 o-tiles x 16 b-tiles x 16 j-splits = 512 blocks of 256 thr (2/CU)
    dim3 grid(ODIM / 128, BDIM / 128, NZ);
    photonic_fused<<<grid, 256, 0, stream>>>(
        X, P, Out,
        (float)phi0, (float)(-2.0 * at), (float)(2.0 * at),
        (float)D, (float)Cnum);
}

// Round 2
// 83.280 us; speedup vs baseline: 1.0503x; 1.0503x over previous
//
#include <hip/hip_runtime.h>
#include <math.h>

// Problem dims (fixed by reference)
#define BDIM 2048
#define ODIM 256
#define IDIM 256
#define NZ   16                     // j-splits
#define JBLK (IDIM / NZ)            // 16 j per block
#define NJQ  (JBLK / 4)             // 4 j-quads
#define ZBASE ((float)(IDIM / NZ))  // 16.0f exactly; per-z share of the +IDIM base

typedef float v2f __attribute__((ext_vector_type(2)));

// out[b,o] = IDIM + C * sum_j 1/(D - 2at*cos(phi0 + x[b,j] + p[o,j]))
//   C = (t^2-1)(1-a^2),  D = 1+(at)^2
// cos(x'+p) = cos x' cos p - sin x' sin p =>
//   den = D + mc*pc + ms*ps,  mc=-2at*cos(phi0+x), ms=2at*sin(phi0+x)
//
// R11: R9's proven 64x64 tile / 4b x 4o microtile (~90 VGPR, free LDS bank
// patterns), but NZ 8 -> 16: grid 1024 -> 2048 blocks at 17.4 KB LDS each.
// R9 ran exactly ONE co-resident round (1024 blocks = 4/CU everywhere), so
// prologue load latency, the barrier, and the atomic drain were never
// overlapped with hot-loop compute. R10 (bigger tile, 2 blocks/CU) proved
// the kernel is latency- not LDS-throughput-bound (-15us). R11 probes the
// opposite direction: launch_bounds(256,5) caps VGPR at 102 -> 5 blocks/CU
// resident (20 waves/CU, +25%) and ~1.6 rounds, so block phases interleave.
// Cost: atomics double to 8.4M lane-ops (sign-informative vs R10).

__global__ __launch_bounds__(256, 5)
void photonic_fused(const float* __restrict__ X,   // [BDIM][IDIM]
                    const float* __restrict__ P,   // [ODIM][IDIM]
                    float* __restrict__ Out,       // [BDIM][ODIM] (+= semantics)
                    float phi0, float m2at, float p2at,
                    float Dc, float Cnum) {
    __shared__ float4 As4[64][2 * NJQ + 1];   // [64][9] = 9216 B (col 8 = pad; row stride 144 B -> +4 banks/row)
    __shared__ float4 SP4[JBLK][2][16];       // [16][2][16] = 8192 B

    const int tid = threadIdx.x;
    const int tx  = tid & 15;            // o sub-index
    const int ty  = tid >> 4;            // b sub-index 0..15
    const int o0  = blockIdx.x * 64;
    const int b0  = blockIdx.y * 64;
    const int j0  = blockIdx.z * JBLK;

    // ---- fused prologue: sincos margins straight into f32 LDS ----
    {
        const int r  = tid >> 2;         // 0..63 : row (b for X, o for P)
        const int jq = tid & 3;          // 0..3  : j-quad
        float s0, c0, s1, c1, s2, c2, s3, c3;

        float4 x = *(const float4*)(X + (size_t)(b0 + r) * IDIM + j0 + 4 * jq);
        __sincosf(phi0 + x.x, &s0, &c0);
        __sincosf(phi0 + x.y, &s1, &c1);
        __sincosf(phi0 + x.z, &s2, &c2);
        __sincosf(phi0 + x.w, &s3, &c3);
        As4[r][2 * jq]     = make_float4(m2at * c0, m2at * c1, m2at * c2, m2at * c3);
        As4[r][2 * jq + 1] = make_float4(p2at * s0, p2at * s1, p2at * s2, p2at * s3);

        float4 pv = *(const float4*)(P + (size_t)(o0 + r) * IDIM + j0 + 4 * jq);
        __sincosf(pv.x, &s0, &c0);
        __sincosf(pv.y, &s1, &c1);
        __sincosf(pv.z, &s2, &c2);
        __sincosf(pv.w, &s3, &c3);
        const int pr  = r >> 5;          // 0/1
        const int hi  = (r >> 4) & 1;    // 0/1
        const int tx_ = r & 15;
        float cs[4] = {c0, c1, c2, c3};
        float ss[4] = {s0, s1, s2, s3};
        #pragma unroll
        for (int jj = 0; jj < 4; ++jj) {
            float* cell = (float*)&SP4[4 * jq + jj][pr][tx_];
            cell[hi]     = cs[jj];
            cell[2 + hi] = ss[jj];
        }
    }
    __syncthreads();

    v2f acc[4][2];
    #pragma unroll
    for (int k = 0; k < 4; ++k) { acc[k][0] = (v2f){0.f, 0.f}; acc[k][1] = (v2f){0.f, 0.f}; }

    const v2f D2 = {Dc, Dc};

    #pragma unroll 2
    for (int jq = 0; jq < NJQ; ++jq) {
        // P operands for this j-quad: 8 x b128, shared across all k
        float4 q0[4], q1[4];
        #pragma unroll
        for (int j = 0; j < 4; ++j) {
            q0[j] = SP4[4 * jq + j][0][tx];
            q1[j] = SP4[4 * jq + j][1][tx];
        }
        #pragma unroll
        for (int k = 0; k < 4; ++k) {
            float4 mc4 = As4[ty + 16 * k][2 * jq];
            float4 ms4 = As4[ty + 16 * k][2 * jq + 1];
            float mcf[4] = {mc4.x, mc4.y, mc4.z, mc4.w};
            float msf[4] = {ms4.x, ms4.y, ms4.z, ms4.w};
            #pragma unroll
            for (int p = 0; p < 2; ++p) {
                const float4* q = (p == 0) ? q0 : q1;
                v2f d[4];
                #pragma unroll
                for (int j = 0; j < 4; ++j) {
                    v2f pc = {q[j].x, q[j].y};
                    v2f ps = {q[j].z, q[j].w};
                    v2f t = __builtin_elementwise_fma((v2f){msf[j], msf[j]}, ps, D2);
                    d[j]  = __builtin_elementwise_fma((v2f){mcf[j], mcf[j]}, pc, t);
                }
                // quad-rcp over the 4 j's, vectorized over the o-pair
                v2f p01 = d[0] * d[1], p23 = d[2] * d[3];
                v2f s01 = d[0] + d[1], s23 = d[2] + d[3];
                v2f n = __builtin_elementwise_fma(s01, p23, s23 * p01);
                v2f qq = p01 * p23;
                v2f r = {__builtin_amdgcn_rcpf(qq.x), __builtin_amdgcn_rcpf(qq.y)};
                acc[k][p] = __builtin_elementwise_fma(n, r, acc[k][p]);
            }
        }
    }

    // ---- atomic epilogue: base folded in as +ZBASE per z-plane ----
    #pragma unroll
    for (int k = 0; k < 4; ++k)
        #pragma unroll
        for (int p = 0; p < 2; ++p) {
            int b = b0 + ty + 16 * k;
            int o = o0 + p * 32 + tx;
            unsafeAtomicAdd(&Out[(size_t)b * ODIM + o],      fmaf(Cnum, acc[k][p].x, ZBASE));
            unsafeAtomicAdd(&Out[(size_t)b * ODIM + o + 16], fmaf(Cnum, acc[k][p].y, ZBASE));
        }
}

extern "C" void kernel_launch(void* const* d_in, const int* in_sizes, int n_in,
                              void* d_out, int out_size, void* d_ws, size_t ws_size,
                              hipStream_t stream) {
    const float* X = (const float*)d_in[0];   // input_matrix [2048,256] f32
    const float* P = (const float*)d_in[1];   // phase_offset [256,256] f32
    float* Out = (float*)d_out;               // [2048,256] f32

    const double RADIUS = 5e-6, KAPPA = 0.1, N_EFF = 3.48, LAMBDA = 1.55e-6, LOSS_A = 0.99;
    const double TWO_PI = 6.283185307179586476925286766559;
    const double t  = sqrt(1.0 - KAPPA);
    const double a  = LOSS_A;
    const double at = a * t;
    const double phi0 = fmod(TWO_PI * N_EFF * (TWO_PI * RADIUS) / LAMBDA, TWO_PI);
    const double D    = 1.0 + at * at;
    const double Cnum = (t * t - 1.0) * (1.0 - a * a);   // num - den (constant)

    // 4 o-tiles x 32 b-tiles x 16 j-splits = 2048 blocks of 256 thr (~5/CU resident)
    dim3 grid(ODIM / 64, BDIM / 64, NZ);
    photonic_fused<<<grid, 256, 0, stream>>>(
        X, P, Out,
        (float)phi0, (float)(-2.0 * at), (float)(2.0 * at),
        (float)D, (float)Cnum);
}

// Round 3
// 80.313 us; speedup vs baseline: 1.0891x; 1.0369x over previous
//
#include <hip/hip_runtime.h>
#include <math.h>

// Problem dims (fixed by reference)
#define BDIM 2048
#define ODIM 256
#define IDIM 256
#define NZ   8                      // j-splits
#define JBLK (IDIM / NZ)            // 32 j per block
#define NJQ  (JBLK / 4)             // 8 j-quads
#define ZBASE ((float)(IDIM / NZ))  // 32.0f; only used by the atomic fallback

typedef float v2f __attribute__((ext_vector_type(2)));

// out[b,o] = IDIM + C * sum_j 1/(D - 2at*cos(phi0 + x[b,j] + p[o,j]))
//   C = (t^2-1)(1-a^2),  D = 1+(at)^2
// cos(x'+p) = cos x' cos p - sin x' sin p =>
//   den = D + mc*pc + ms*ps,  mc=-2at*cos(phi0+x), ms=2at*sin(phi0+x)
//
// R12: R9's structure verbatim (NZ=8, 64x64 tile, 4b x 4o, 4 blocks/CU,
// free LDS bank patterns) but the atomic epilogue is replaced by plain
// stores of per-z partials into WS[z][b][o] (16.8 MB workspace), reduced
// by a second tiny kernel. Rationale: R10 (+4.2M atomics, occ down) and
// R11 (+4.2M atomics, occ up) both regressed 10-15us => marginal atomic
// cost ~3 ns/lane-atomic => R9's own 4.2M cross-XCD atomics are ~10-15us
// of its 32us. Private per-z stores have zero contention (2.7us of write
// BW, pipeline-hidden); the reduce kernel is ~4-5us of L3-resident BW.
// ATOMIC=1 fallback (R9 exact) if ws_size < 16.8 MB.

template<int ATOMIC>
__global__ __launch_bounds__(256, 4)
void photonic_fused(const float* __restrict__ X,   // [BDIM][IDIM]
                    const float* __restrict__ P,   // [ODIM][IDIM]
                    float* __restrict__ Out,       // ATOMIC: [BDIM][ODIM] +=
                                                   // else:   WS [NZ][BDIM][ODIM] store
                    float phi0, float m2at, float p2at,
                    float Dc, float Cnum) {
    __shared__ float4 As4[64][17];       // 17408 B (slot 16 = pad)
    __shared__ float4 SP4[JBLK][2][16];  // 16384 B

    const int tid = threadIdx.x;
    const int tx  = tid & 15;            // o sub-index
    const int ty  = tid >> 4;            // b sub-index 0..15
    const int o0  = blockIdx.x * 64;
    const int b0  = blockIdx.y * 64;
    const int j0  = blockIdx.z * JBLK;

    // ---- fused prologue: sincos margins straight into f32 LDS ----
    #pragma unroll
    for (int i = 0; i < 2; ++i) {
        const int r  = (tid >> 3) + 32 * i;   // 0..63
        const int jq = tid & 7;               // 0..7
        float s0, c0, s1, c1, s2, c2, s3, c3;

        float4 x = *(const float4*)(X + (size_t)(b0 + r) * IDIM + j0 + 4 * jq);
        __sincosf(phi0 + x.x, &s0, &c0);
        __sincosf(phi0 + x.y, &s1, &c1);
        __sincosf(phi0 + x.z, &s2, &c2);
        __sincosf(phi0 + x.w, &s3, &c3);
        As4[r][2 * jq]     = make_float4(m2at * c0, m2at * c1, m2at * c2, m2at * c3);
        As4[r][2 * jq + 1] = make_float4(p2at * s0, p2at * s1, p2at * s2, p2at * s3);

        float4 pv = *(const float4*)(P + (size_t)(o0 + r) * IDIM + j0 + 4 * jq);
        __sincosf(pv.x, &s0, &c0);
        __sincosf(pv.y, &s1, &c1);
        __sincosf(pv.z, &s2, &c2);
        __sincosf(pv.w, &s3, &c3);
        const int pr  = r >> 5;               // 0/1
        const int hi  = (r >> 4) & 1;         // 0/1
        const int tx_ = r & 15;
        float cs[4] = {c0, c1, c2, c3};
        float ss[4] = {s0, s1, s2, s3};
        #pragma unroll
        for (int jj = 0; jj < 4; ++jj) {
            float* cell = (float*)&SP4[4 * jq + jj][pr][tx_];
            cell[hi]     = cs[jj];
            cell[2 + hi] = ss[jj];
        }
    }
    __syncthreads();

    v2f acc[4][2];
    #pragma unroll
    for (int k = 0; k < 4; ++k) { acc[k][0] = (v2f){0.f, 0.f}; acc[k][1] = (v2f){0.f, 0.f}; }

    const v2f D2 = {Dc, Dc};

    #pragma unroll 2
    for (int jq = 0; jq < NJQ; ++jq) {
        // P operands for this j-quad: 8 x b128, shared across all k
        float4 q0[4], q1[4];
        #pragma unroll
        for (int j = 0; j < 4; ++j) {
            q0[j] = SP4[4 * jq + j][0][tx];
            q1[j] = SP4[4 * jq + j][1][tx];
        }
        #pragma unroll
        for (int k = 0; k < 4; ++k) {
            float4 mc4 = As4[ty + 16 * k][2 * jq];
            float4 ms4 = As4[ty + 16 * k][2 * jq + 1];
            float mcf[4] = {mc4.x, mc4.y, mc4.z, mc4.w};
            float msf[4] = {ms4.x, ms4.y, ms4.z, ms4.w};
            #pragma unroll
            for (int p = 0; p < 2; ++p) {
                const float4* q = (p == 0) ? q0 : q1;
                v2f d[4];
                #pragma unroll
                for (int j = 0; j < 4; ++j) {
                    v2f pc = {q[j].x, q[j].y};
                    v2f ps = {q[j].z, q[j].w};
                    v2f t = __builtin_elementwise_fma((v2f){msf[j], msf[j]}, ps, D2);
                    d[j]  = __builtin_elementwise_fma((v2f){mcf[j], mcf[j]}, pc, t);
                }
                // quad-rcp over the 4 j's, vectorized over the o-pair
                v2f p01 = d[0] * d[1], p23 = d[2] * d[3];
                v2f s01 = d[0] + d[1], s23 = d[2] + d[3];
                v2f n = __builtin_elementwise_fma(s01, p23, s23 * p01);
                v2f qq = p01 * p23;
                v2f r = {__builtin_amdgcn_rcpf(qq.x), __builtin_amdgcn_rcpf(qq.y)};
                acc[k][p] = __builtin_elementwise_fma(n, r, acc[k][p]);
            }
        }
    }

    // ---- epilogue ----
    if (ATOMIC) {
        // fallback: atomic += with base folded in as +ZBASE per z-plane
        #pragma unroll
        for (int k = 0; k < 4; ++k)
            #pragma unroll
            for (int p = 0; p < 2; ++p) {
                int b = b0 + ty + 16 * k;
                int o = o0 + p * 32 + tx;
                unsafeAtomicAdd(&Out[(size_t)b * ODIM + o],      fmaf(Cnum, acc[k][p].x, ZBASE));
                unsafeAtomicAdd(&Out[(size_t)b * ODIM + o + 16], fmaf(Cnum, acc[k][p].y, ZBASE));
            }
    } else {
        // contention-free: plain stores of raw partial sums to this z's plane
        float* W = Out + (size_t)blockIdx.z * (BDIM * ODIM);
        #pragma unroll
        for (int k = 0; k < 4; ++k)
            #pragma unroll
            for (int p = 0; p < 2; ++p) {
                int b = b0 + ty + 16 * k;
                int o = o0 + p * 32 + tx;
                W[(size_t)b * ODIM + o]      = acc[k][p].x;
                W[(size_t)b * ODIM + o + 16] = acc[k][p].y;
            }
    }
}

// Phase 2: Out[b,o] = IDIM + Cnum * sum_z WS[z][b][o].  float4 per thread.
__global__ __launch_bounds__(256)
void photonic_reduce(const float* __restrict__ WS, float* __restrict__ Out,
                     float Cnum) {
    const int i4 = blockIdx.x * 256 + threadIdx.x;      // 0 .. B*O/4-1
    const float4* W = (const float4*)WS;
    const int plane = BDIM * ODIM / 4;                  // 131072 float4s
    float4 s = W[i4];
    #pragma unroll
    for (int z = 1; z < NZ; ++z) {
        float4 v = W[(size_t)z * plane + i4];
        s.x += v.x; s.y += v.y; s.z += v.z; s.w += v.w;
    }
    float4 r = make_float4(fmaf(Cnum, s.x, (float)IDIM),
                           fmaf(Cnum, s.y, (float)IDIM),
                           fmaf(Cnum, s.z, (float)IDIM),
                           fmaf(Cnum, s.w, (float)IDIM));
    ((float4*)Out)[i4] = r;
}

extern "C" void kernel_launch(void* const* d_in, const int* in_sizes, int n_in,
                              void* d_out, int out_size, void* d_ws, size_t ws_size,
                              hipStream_t stream) {
    const float* X = (const float*)d_in[0];   // input_matrix [2048,256] f32
    const float* P = (const float*)d_in[1];   // phase_offset [256,256] f32
    float* Out = (float*)d_out;               // [2048,256] f32

    const double RADIUS = 5e-6, KAPPA = 0.1, N_EFF = 3.48, LAMBDA = 1.55e-6, LOSS_A = 0.99;
    const double TWO_PI = 6.283185307179586476925286766559;
    const double t  = sqrt(1.0 - KAPPA);
    const double a  = LOSS_A;
    const double at = a * t;
    const double phi0 = fmod(TWO_PI * N_EFF * (TWO_PI * RADIUS) / LAMBDA, TWO_PI);
    const double D    = 1.0 + at * at;
    const double Cnum = (t * t - 1.0) * (1.0 - a * a);   // num - den (constant)

    const size_t ws_need = (size_t)NZ * BDIM * ODIM * sizeof(float);  // 16.8 MB

    dim3 grid(ODIM / 64, BDIM / 64, NZ);    // 1024 blocks of 256 thr (4/CU)
    if (d_ws != nullptr && ws_size >= ws_need) {
        float* WS = (float*)d_ws;
        photonic_fused<0><<<grid, 256, 0, stream>>>(
            X, P, WS,
            (float)phi0, (float)(-2.0 * at), (float)(2.0 * at),
            (float)D, (float)Cnum);
        photonic_reduce<<<dim3(BDIM * ODIM / 1024), 256, 0, stream>>>(
            WS, Out, (float)Cnum);
    } else {
        photonic_fused<1><<<grid, 256, 0, stream>>>(
            X, P, Out,
            (float)phi0, (float)(-2.0 * at), (float)(2.0 * at),
            (float)D, (float)Cnum);
    }
}

// Round 4
// 71.717 us; speedup vs baseline: 1.2197x; 1.1199x over previous
//
#include <hip/hip_runtime.h>
#include <math.h>

// Problem dims (fixed by reference)
#define BDIM 2048
#define ODIM 256
#define IDIM 256
#define NZ   8                      // j-splits
#define JBLK (IDIM / NZ)            // 32 j per block
#define NJQ  (JBLK / 4)             // 8 j-quads
#define ZBASE ((float)(IDIM / NZ))  // 32.0f; per-z share of the +IDIM base

typedef float v2f __attribute__((ext_vector_type(2)));

// out[b,o] = IDIM + C * sum_j 1/(D - 2at*cos(phi0 + x[b,j] + p[o,j]))
//   C = (t^2-1)(1-a^2),  D = 1+(at)^2
// cos(x'+p) = cos x' cos p - sin x' sin p =>
//   den = D + mc*pc + ms*ps,  mc=-2at*cos(phi0+x), ms=2at*sin(phi0+x)
//
// R13: latency-bound diagnosis. R10 (half LDS traffic, 8 waves/CU) was
// +15us and R12 (no atomics) was +0 => neither LDS throughput nor atomics
// bind; the cost is per-wave {read-burst -> lgkmcnt -> FMA chain} latency
// at only 4 waves/SIMD. Fix: same 64x64 tile / NZ=8 / LDS layouts / 1024
// blocks, but 512 threads per block, each thread 2b x 4o (hf = tid>>8
// picks the k-half). VGPR ~halves => launch_bounds(512,6) gives 6
// waves/SIMD = 24 waves/CU (+50%) and per-wave chains halve. LDS insts
// +50% (6 B/cell-j) -- fine, pipe has >=2x headroom per R10. Atomics
// unchanged (4.2M; each cell owned by one thread).

__global__ __launch_bounds__(512, 6)
void photonic_fused(const float* __restrict__ X,   // [BDIM][IDIM]
                    const float* __restrict__ P,   // [ODIM][IDIM]
                    float* __restrict__ Out,       // [BDIM][ODIM] (+= semantics)
                    float phi0, float m2at, float p2at,
                    float Dc, float Cnum) {
    __shared__ float4 As4[64][17];       // 17408 B (slot 16 = pad)
    __shared__ float4 SP4[JBLK][2][16];  // 16384 B

    const int tid = threadIdx.x;
    const int tx  = tid & 15;            // o sub-index 0..15
    const int ty  = (tid >> 4) & 15;     // b sub-index 0..15
    const int hf  = tid >> 8;            // k-half 0/1
    const int o0  = blockIdx.x * 64;
    const int b0  = blockIdx.y * 64;
    const int j0  = blockIdx.z * JBLK;

    // ---- fused prologue: one float4 of X and P per thread ----
    {
        const int r  = tid >> 3;         // 0..63 : row (b for X, o for P)
        const int jq = tid & 7;          // 0..7  : j-quad
        float s0, c0, s1, c1, s2, c2, s3, c3;

        float4 x = *(const float4*)(X + (size_t)(b0 + r) * IDIM + j0 + 4 * jq);
        __sincosf(phi0 + x.x, &s0, &c0);
        __sincosf(phi0 + x.y, &s1, &c1);
        __sincosf(phi0 + x.z, &s2, &c2);
        __sincosf(phi0 + x.w, &s3, &c3);
        As4[r][2 * jq]     = make_float4(m2at * c0, m2at * c1, m2at * c2, m2at * c3);
        As4[r][2 * jq + 1] = make_float4(p2at * s0, p2at * s1, p2at * s2, p2at * s3);

        float4 pv = *(const float4*)(P + (size_t)(o0 + r) * IDIM + j0 + 4 * jq);
        __sincosf(pv.x, &s0, &c0);
        __sincosf(pv.y, &s1, &c1);
        __sincosf(pv.z, &s2, &c2);
        __sincosf(pv.w, &s3, &c3);
        const int pr  = r >> 5;          // 0/1
        const int hi  = (r >> 4) & 1;    // 0/1
        const int tx_ = r & 15;
        float cs[4] = {c0, c1, c2, c3};
        float ss[4] = {s0, s1, s2, s3};
        #pragma unroll
        for (int jj = 0; jj < 4; ++jj) {
            float* cell = (float*)&SP4[4 * jq + jj][pr][tx_];
            cell[hi]     = cs[jj];
            cell[2 + hi] = ss[jj];
        }
    }
    __syncthreads();

    v2f acc[2][2];
    #pragma unroll
    for (int k = 0; k < 2; ++k) { acc[k][0] = (v2f){0.f, 0.f}; acc[k][1] = (v2f){0.f, 0.f}; }

    const v2f D2 = {Dc, Dc};

    #pragma unroll 2
    for (int jq = 0; jq < NJQ; ++jq) {
        // P operands for this j-quad: 8 x b128, shared across both k's
        float4 q0[4], q1[4];
        #pragma unroll
        for (int j = 0; j < 4; ++j) {
            q0[j] = SP4[4 * jq + j][0][tx];
            q1[j] = SP4[4 * jq + j][1][tx];
        }
        #pragma unroll
        for (int k = 0; k < 2; ++k) {
            const int row = ty + 16 * (2 * hf + k);
            float4 mc4 = As4[row][2 * jq];
            float4 ms4 = As4[row][2 * jq + 1];
            float mcf[4] = {mc4.x, mc4.y, mc4.z, mc4.w};
            float msf[4] = {ms4.x, ms4.y, ms4.z, ms4.w};
            #pragma unroll
            for (int p = 0; p < 2; ++p) {
                const float4* q = (p == 0) ? q0 : q1;
                v2f d[4];
                #pragma unroll
                for (int j = 0; j < 4; ++j) {
                    v2f pc = {q[j].x, q[j].y};
                    v2f ps = {q[j].z, q[j].w};
                    v2f t = __builtin_elementwise_fma((v2f){msf[j], msf[j]}, ps, D2);
                    d[j]  = __builtin_elementwise_fma((v2f){mcf[j], mcf[j]}, pc, t);
                }
                // quad-rcp over the 4 j's, vectorized over the o-pair
                v2f p01 = d[0] * d[1], p23 = d[2] * d[3];
                v2f s01 = d[0] + d[1], s23 = d[2] + d[3];
                v2f n = __builtin_elementwise_fma(s01, p23, s23 * p01);
                v2f qq = p01 * p23;
                v2f r = {__builtin_amdgcn_rcpf(qq.x), __builtin_amdgcn_rcpf(qq.y)};
                acc[k][p] = __builtin_elementwise_fma(n, r, acc[k][p]);
            }
        }
    }

    // ---- atomic epilogue: base folded in as +ZBASE per z-plane ----
    #pragma unroll
    for (int k = 0; k < 2; ++k)
        #pragma unroll
        for (int p = 0; p < 2; ++p) {
            int b = b0 + ty + 16 * (2 * hf + k);
            int o = o0 + p * 32 + tx;
            unsafeAtomicAdd(&Out[(size_t)b * ODIM + o],      fmaf(Cnum, acc[k][p].x, ZBASE));
            unsafeAtomicAdd(&Out[(size_t)b * ODIM + o + 16], fmaf(Cnum, acc[k][p].y, ZBASE));
        }
}

extern "C" void kernel_launch(void* const* d_in, const int* in_sizes, int n_in,
                              void* d_out, int out_size, void* d_ws, size_t ws_size,
                              hipStream_t stream) {
    const float* X = (const float*)d_in[0];   // input_matrix [2048,256] f32
    const float* P = (const float*)d_in[1];   // phase_offset [256,256] f32
    float* Out = (float*)d_out;               // [2048,256] f32

    const double RADIUS = 5e-6, KAPPA = 0.1, N_EFF = 3.48, LAMBDA = 1.55e-6, LOSS_A = 0.99;
    const double TWO_PI = 6.283185307179586476925286766559;
    const double t  = sqrt(1.0 - KAPPA);
    const double a  = LOSS_A;
    const double at = a * t;
    const double phi0 = fmod(TWO_PI * N_EFF * (TWO_PI * RADIUS) / LAMBDA, TWO_PI);
    const double D    = 1.0 + at * at;
    const double Cnum = (t * t - 1.0) * (1.0 - a * a);   // num - den (constant)

    // 4 o-tiles x 32 b-tiles x 8 j-splits = 1024 blocks of 512 thr (3/CU, 24 waves/CU)
    dim3 grid(ODIM / 64, BDIM / 64, NZ);
    photonic_fused<<<grid, 512, 0, stream>>>(
        X, P, Out,
        (float)phi0, (float)(-2.0 * at), (float)(2.0 * at),
        (float)D, (float)Cnum);
}